// Round 1
// baseline (820.000 us; speedup 1.0000x reference)
//
#include <hip/hip_runtime.h>
#include <math.h>

#define Bb 8
#define Hh 8
#define LQ 2048
#define LK 2048
#define Dd 64
#define Uu 40
#define NCH 32
#define CHUNK (LK / NCH)   // 64

__device__ __forceinline__ float wave_reduce_sum(float v) {
#pragma unroll
    for (int off = 32; off > 0; off >>= 1)
        v += __shfl_xor(v, off, 64);
    return v;
}

// ---------------- Stage 1: M[b,h,q] = max_s(QK_s) - mean_s(QK_s) ----------------
__global__ __launch_bounds__(256) void k_sampleM(
    const float* __restrict__ Qp, const float* __restrict__ Kp,
    const int* __restrict__ idxs, float* __restrict__ M)
{
    int wid  = blockIdx.x * 4 + (threadIdx.x >> 6);   // one wave per (b,h,q)
    int lane = threadIdx.x & 63;
    int q  = wid & (LQ - 1);
    int bh = wid >> 11;           // LQ = 2048
    int b = bh >> 3, h = bh & 7;

    float qv = Qp[(((size_t)b * LQ + q) * Hh + h) * Dd + lane];
    int myidx = (lane < Uu) ? idxs[q * Uu + lane] : 0;

    float mx = -INFINITY, sm = 0.f;
#pragma unroll 4
    for (int s = 0; s < Uu; ++s) {
        int kidx = __shfl(myidx, s, 64);
        float kv = Kp[(((size_t)b * LK + kidx) * Hh + h) * Dd + lane];
        float dot = wave_reduce_sum(qv * kv);
        mx = fmaxf(mx, dot);
        sm += dot;
    }
    if (lane == 0) M[bh * LQ + q] = mx - sm * (1.0f / Uu);
}

// ---------------- Stage 2: top-40 per (b,h), build sel map ----------------
__global__ __launch_bounds__(256) void k_topk(
    const float* __restrict__ M, int* __restrict__ Mtop, int* __restrict__ sel)
{
    int bh = blockIdx.x;
    int t  = threadIdx.x;
    __shared__ float Ml[LQ];
    __shared__ float sv[256];
    __shared__ int   si[256];

    for (int j = t; j < LQ; j += 256) {
        Ml[j] = M[bh * LQ + j];
        sel[bh * LQ + j] = -1;
    }
    __syncthreads();

    for (int u = 0; u < Uu; ++u) {
        float v = -INFINITY; int id = LQ;
        for (int j = t; j < LQ; j += 256) {
            float x = Ml[j];
            if (x > v) { v = x; id = j; }   // ascending j => lowest index on ties
        }
        sv[t] = v; si[t] = id;
        __syncthreads();
        for (int s = 128; s > 0; s >>= 1) {
            if (t < s) {
                float ov = sv[t + s]; int oi = si[t + s];
                if (ov > sv[t] || (ov == sv[t] && oi < si[t])) { sv[t] = ov; si[t] = oi; }
            }
            __syncthreads();
        }
        if (t == 0) {
            int w = si[0];
            Mtop[bh * Uu + u] = w;
            sel[bh * LQ + w] = u;
            Ml[w] = -INFINITY;
        }
        __syncthreads();
    }
}

// ---------------- Stage 3: causal softmax attention for selected queries ----------------
__global__ __launch_bounds__(256) void k_attn(
    const float* __restrict__ Qp, const float* __restrict__ Kp,
    const float* __restrict__ Vp, const int* __restrict__ Mtop,
    float* __restrict__ attn)
{
    int bu = blockIdx.x;
    int bh = bu / Uu, u = bu % Uu;
    int b = bh >> 3, h = bh & 7;
    int p = Mtop[bh * Uu + u];

    int lane = threadIdx.x & 63, wave = threadIdx.x >> 6;
    float qv = Qp[(((size_t)b * LQ + p) * Hh + h) * Dd + lane];

    float m = -INFINITY, l = 0.f, acc = 0.f;
    for (int k = wave; k <= p; k += 4) {
        size_t base = (((size_t)b * LK + k) * Hh + h) * Dd + lane;
        float kv = Kp[base];
        float s  = wave_reduce_sum(qv * kv) * 0.125f;   // 1/sqrt(64)
        float nm = fmaxf(m, s);
        float sc = expf(m - nm);
        float e  = expf(s - nm);
        float vv = Vp[base];
        l   = l * sc + e;
        acc = acc * sc + e * vv;
        m = nm;
    }

    __shared__ float smx[4], sl[4], sacc[4][Dd];
    if (lane == 0) { smx[wave] = m; sl[wave] = l; }
    sacc[wave][lane] = acc;
    __syncthreads();

    if (threadIdx.x < Dd) {
        int d = threadIdx.x;
        float gm = fmaxf(fmaxf(smx[0], smx[1]), fmaxf(smx[2], smx[3]));
        float L = 0.f, A = 0.f;
#pragma unroll
        for (int w = 0; w < 4; ++w) {
            float sc = expf(smx[w] - gm);   // empty wave: smx=-inf -> sc=0
            L += sl[w] * sc;
            A += sacc[w][d] * sc;
        }
        attn[(bh * Uu + u) * Dd + d] = A / L;
    }
}

// ---------------- Stage 4a: per-chunk partial sums of V along L ----------------
__global__ __launch_bounds__(64) void k_part(
    const float* __restrict__ Vp, float* __restrict__ part)
{
    int c  = blockIdx.x & (NCH - 1);
    int bh = blockIdx.x >> 5;           // NCH = 32
    int b = bh >> 3, h = bh & 7;
    int d = threadIdx.x;

    float s = 0.f;
    int l0 = c * CHUNK;
#pragma unroll 4
    for (int l = l0; l < l0 + CHUNK; ++l)
        s += Vp[(((size_t)b * LK + l) * Hh + h) * Dd + d];
    part[(bh * NCH + c) * Dd + d] = s;
}

// ---------------- Stage 4b: cumsum + scatter attn rows -> output ----------------
__global__ __launch_bounds__(64) void k_scan(
    const float* __restrict__ Vp, const float* __restrict__ part,
    const int* __restrict__ sel, const float* __restrict__ attn,
    float* __restrict__ out)
{
    int c  = blockIdx.x & (NCH - 1);
    int bh = blockIdx.x >> 5;
    int b = bh >> 3, h = bh & 7;
    int d = threadIdx.x;

    float run = 0.f;
    for (int cc = 0; cc < c; ++cc)
        run += part[(bh * NCH + cc) * Dd + d];

    int l0 = c * CHUNK;
    for (int l = l0; l < l0 + CHUNK; ++l) {
        run += Vp[(((size_t)b * LK + l) * Hh + h) * Dd + d];
        int s = sel[bh * LQ + l];
        float o = (s >= 0) ? attn[(bh * Uu + s) * Dd + d] : run;
        out[(((size_t)b * LQ + l) * Hh + h) * Dd + d] = o;
    }
}

extern "C" void kernel_launch(void* const* d_in, const int* in_sizes, int n_in,
                              void* d_out, int out_size, void* d_ws, size_t ws_size,
                              hipStream_t stream) {
    const float* Qp   = (const float*)d_in[0];
    const float* Kp   = (const float*)d_in[1];
    const float* Vp   = (const float*)d_in[2];
    const int*   idxs = (const int*)d_in[3];
    float* out = (float*)d_out;

    char* w = (char*)d_ws;
    float* M    = (float*)(w);                               // 131072 f (512K)
    int*   sel  = (int*)  (w + 512 * 1024);                  // 131072 i (512K)
    float* attn = (float*)(w + 1024 * 1024);                 // 163840 f (640K)
    int*   Mtop = (int*)  (w + 1024 * 1024 + 640 * 1024);    //   2560 i (10K)
    float* part = (float*)(w + 1024 * 1024 + 656 * 1024);    // 131072 f (512K)

    k_sampleM<<<(Bb * Hh * LQ) / 4, 256, 0, stream>>>(Qp, Kp, idxs, M);
    k_topk<<<Bb * Hh, 256, 0, stream>>>(M, Mtop, sel);
    k_attn<<<Bb * Hh * Uu, 256, 0, stream>>>(Qp, Kp, Vp, Mtop, attn);
    k_part<<<Bb * Hh * NCH, 64, 0, stream>>>(Vp, part);
    k_scan<<<Bb * Hh * NCH, 64, 0, stream>>>(Vp, part, sel, attn, out);
}

// Round 2
// 490.460 us; speedup vs baseline: 1.6719x; 1.6719x over previous
//
#include <hip/hip_runtime.h>
#include <math.h>

#define Bb 8
#define Hh 8
#define LQ 2048
#define LK 2048
#define Dd 64
#define Uu 40
#define NCH 32
#define CHUNK (LK / NCH)   // 64

__device__ __forceinline__ float dot4(float4 a, float4 b) {
    return a.x * b.x + a.y * b.y + a.z * b.z + a.w * b.w;
}

// ---------------- Stage 1: M[b,h,q] = max_s(QK_s) - mean_s(QK_s) ----------------
// quad-per-query: 4 lanes each own 16 d-elements; 2 DPP shuffles per sample.
__global__ __launch_bounds__(256) void k_sampleM(
    const float* __restrict__ Qp, const float* __restrict__ Kp,
    const int* __restrict__ idxs, float* __restrict__ M)
{
    int bh = blockIdx.x & 63;     // bh-major => same-bh blocks share an XCD
    int qt = blockIdx.x >> 6;     // 0..31 (64 queries per block)
    int b = bh >> 3, h = bh & 7;
    int t = threadIdx.x;
    int lq = t >> 2;              // 0..63 local query
    int r  = t & 3;               // quad lane: d-range r*16..r*16+15
    int q  = qt * 64 + lq;

    __shared__ int sIdx[64 * Uu];
    for (int i = t; i < 64 * Uu; i += 256)
        sIdx[i] = idxs[(qt * 64) * Uu + i];
    __syncthreads();

    const float4* Qv = reinterpret_cast<const float4*>(
        Qp + (((size_t)b * LQ + q) * Hh + h) * Dd + r * 16);
    float4 q0 = Qv[0], q1 = Qv[1], q2 = Qv[2], q3 = Qv[3];

    float mx = -INFINITY, sm = 0.f;
#pragma unroll 4
    for (int s = 0; s < Uu; ++s) {
        int kidx = sIdx[lq * Uu + s];
        const float4* Kv = reinterpret_cast<const float4*>(
            Kp + (((size_t)b * LK + kidx) * Hh + h) * Dd + r * 16);
        float4 k0 = Kv[0], k1 = Kv[1], k2 = Kv[2], k3 = Kv[3];
        float p = dot4(q0, k0) + dot4(q1, k1) + dot4(q2, k2) + dot4(q3, k3);
        p += __shfl_xor(p, 1, 64);
        p += __shfl_xor(p, 2, 64);
        mx = fmaxf(mx, p);
        sm += p;
    }
    if (r == 0) M[bh * LQ + q] = mx - sm * (1.0f / Uu);
}

// ---------------- Stage 2: top-40 per (b,h), build sel map ----------------
__global__ __launch_bounds__(256) void k_topk(
    const float* __restrict__ M, int* __restrict__ Mtop, int* __restrict__ sel)
{
    int bh = blockIdx.x;
    int t  = threadIdx.x;
    __shared__ float Ml[LQ];
    __shared__ float sv[256];
    __shared__ int   si[256];

    for (int j = t; j < LQ; j += 256) {
        Ml[j] = M[bh * LQ + j];
        sel[bh * LQ + j] = -1;
    }
    __syncthreads();

    for (int u = 0; u < Uu; ++u) {
        float v = -INFINITY; int id = LQ;
        for (int j = t; j < LQ; j += 256) {
            float x = Ml[j];
            if (x > v) { v = x; id = j; }   // ascending j => lowest index on ties
        }
        sv[t] = v; si[t] = id;
        __syncthreads();
        for (int s = 128; s > 0; s >>= 1) {
            if (t < s) {
                float ov = sv[t + s]; int oi = si[t + s];
                if (ov > sv[t] || (ov == sv[t] && oi < si[t])) { sv[t] = ov; si[t] = oi; }
            }
            __syncthreads();
        }
        if (t == 0) {
            int w = si[0];
            Mtop[bh * Uu + u] = w;
            sel[bh * LQ + w] = u;
            Ml[w] = -INFINITY;
        }
        __syncthreads();
    }
}

// ---------------- Stage 3: causal softmax attention for selected queries ----------------
// lane-per-key tiles of 64; one reduce per tile; PV via LDS-broadcast weights.
__global__ __launch_bounds__(256) void k_attn(
    const float* __restrict__ Qp, const float* __restrict__ Kp,
    const float* __restrict__ Vp, const int* __restrict__ Mtop,
    float* __restrict__ attn)
{
    int bh = blockIdx.x & 63;     // bh-major => same-bh blocks share an XCD
    int u  = blockIdx.x >> 6;     // 0..39
    int b = bh >> 3, h = bh & 7;
    int p = Mtop[bh * Uu + u];

    int lane = threadIdx.x & 63, wave = threadIdx.x >> 6;

    // full Q row in registers (identical across threads)
    const float4* Qv = reinterpret_cast<const float4*>(
        Qp + (((size_t)b * LQ + p) * Hh + h) * Dd);
    float4 qr[16];
#pragma unroll
    for (int j = 0; j < 16; ++j) qr[j] = Qv[j];

    __shared__ float sE[4][64];

    float m = -INFINITY, l = 0.f, acc = 0.f;
    int ntiles = (p >> 6) + 1;
    for (int tw = wave; tw < ntiles; tw += 4) {
        int k = tw * 64 + lane;   // k <= 2047 always (tile start <= p)
        // score for this lane's key
        const float4* Kv = reinterpret_cast<const float4*>(
            Kp + (((size_t)b * LK + k) * Hh + h) * Dd);
        float d0 = 0.f;
#pragma unroll 4
        for (int j = 0; j < 16; ++j) d0 += dot4(qr[j], Kv[j]);
        float s = (k <= p) ? d0 * 0.125f : -INFINITY;

        // tile max (one reduce per 64 keys)
        float tm = s;
#pragma unroll
        for (int off = 32; off > 0; off >>= 1)
            tm = fmaxf(tm, __shfl_xor(tm, off, 64));
        float nm = fmaxf(m, tm);          // tile has >=1 valid key => finite
        float sc = expf(m - nm);          // first tile: exp(-inf)=0
        float e  = expf(s - nm);          // masked lanes: exp(-inf)=0
        float ls = e;
#pragma unroll
        for (int off = 32; off > 0; off >>= 1)
            ls += __shfl_xor(ls, off, 64);
        l = l * sc + ls;
        m = nm;

        // PV: flip ownership to lane-per-d; broadcast weights via LDS
        sE[wave][lane] = e;
        const float4* Ev = reinterpret_cast<const float4*>(sE[wave]);
        const float* Vbase = Vp + (((size_t)b * LK + tw * 64) * Hh + h) * Dd + lane;
        float a = acc * sc;
#pragma unroll 4
        for (int kk = 0; kk < 16; ++kk) {
            float4 e4 = Ev[kk];
            a += e4.x * Vbase[(size_t)(kk * 4 + 0) * (Hh * Dd)];
            a += e4.y * Vbase[(size_t)(kk * 4 + 1) * (Hh * Dd)];
            a += e4.z * Vbase[(size_t)(kk * 4 + 2) * (Hh * Dd)];
            a += e4.w * Vbase[(size_t)(kk * 4 + 3) * (Hh * Dd)];
        }
        acc = a;
    }

    __shared__ float smx[4], sl[4], sacc[4][Dd];
    if (lane == 0) { smx[wave] = m; sl[wave] = l; }
    sacc[wave][lane] = acc;
    __syncthreads();

    if (threadIdx.x < Dd) {
        int d = threadIdx.x;
        float gm = fmaxf(fmaxf(smx[0], smx[1]), fmaxf(smx[2], smx[3]));
        float L = 0.f, A = 0.f;
#pragma unroll
        for (int w = 0; w < 4; ++w) {
            float sc = expf(smx[w] - gm);   // empty wave: smx=-inf -> 0
            L += sl[w] * sc;
            A += sacc[w][d] * sc;
        }
        attn[(bh * Uu + u) * Dd + d] = A / L;
    }
}

// ---------------- Stage 4a: per-chunk partial sums of V along L ----------------
__global__ __launch_bounds__(64) void k_part(
    const float* __restrict__ Vp, float* __restrict__ part)
{
    int c  = blockIdx.x & (NCH - 1);
    int bh = blockIdx.x >> 5;           // NCH = 32
    int b = bh >> 3, h = bh & 7;
    int d = threadIdx.x;

    float s = 0.f;
    int l0 = c * CHUNK;
#pragma unroll 4
    for (int l = l0; l < l0 + CHUNK; ++l)
        s += Vp[(((size_t)b * LK + l) * Hh + h) * Dd + d];
    part[(bh * NCH + c) * Dd + d] = s;
}

// ---------------- Stage 4b: cumsum + scatter attn rows -> output ----------------
__global__ __launch_bounds__(64) void k_scan(
    const float* __restrict__ Vp, const float* __restrict__ part,
    const int* __restrict__ sel, const float* __restrict__ attn,
    float* __restrict__ out)
{
    int c  = blockIdx.x & (NCH - 1);
    int bh = blockIdx.x >> 5;
    int b = bh >> 3, h = bh & 7;
    int d = threadIdx.x;

    float run = 0.f;
    for (int cc = 0; cc < c; ++cc)
        run += part[(bh * NCH + cc) * Dd + d];

    int l0 = c * CHUNK;
    for (int l = l0; l < l0 + CHUNK; ++l) {
        run += Vp[(((size_t)b * LK + l) * Hh + h) * Dd + d];
        int s = sel[bh * LQ + l];
        float o = (s >= 0) ? attn[(bh * Uu + s) * Dd + d] : run;
        out[(((size_t)b * LQ + l) * Hh + h) * Dd + d] = o;
    }
}

extern "C" void kernel_launch(void* const* d_in, const int* in_sizes, int n_in,
                              void* d_out, int out_size, void* d_ws, size_t ws_size,
                              hipStream_t stream) {
    const float* Qp   = (const float*)d_in[0];
    const float* Kp   = (const float*)d_in[1];
    const float* Vp   = (const float*)d_in[2];
    const int*   idxs = (const int*)d_in[3];
    float* out = (float*)d_out;

    char* w = (char*)d_ws;
    float* M    = (float*)(w);                               // 131072 f (512K)
    int*   sel  = (int*)  (w + 512 * 1024);                  // 131072 i (512K)
    float* attn = (float*)(w + 1024 * 1024);                 // 163840 f (640K)
    int*   Mtop = (int*)  (w + 1024 * 1024 + 640 * 1024);    //   2560 i (10K)
    float* part = (float*)(w + 1024 * 1024 + 656 * 1024);    // 131072 f (512K)

    k_sampleM<<<Bb * Hh * (LQ / 64), 256, 0, stream>>>(Qp, Kp, idxs, M);
    k_topk<<<Bb * Hh, 256, 0, stream>>>(M, Mtop, sel);
    k_attn<<<Bb * Hh * Uu, 256, 0, stream>>>(Qp, Kp, Vp, Mtop, attn);
    k_part<<<Bb * Hh * NCH, 64, 0, stream>>>(Vp, part);
    k_scan<<<Bb * Hh * NCH, 64, 0, stream>>>(Vp, part, sel, attn, out);
}

// Round 3
// 241.235 us; speedup vs baseline: 3.3992x; 2.0331x over previous
//
#include <hip/hip_runtime.h>
#include <math.h>

#define Bb 8
#define Hh 8
#define LQ 2048
#define LK 2048
#define Dd 64
#define Uu 40
#define NCH 32
#define CHUNK (LK / NCH)   // 64
#define NSPL 8
#define CK (LK / NSPL)     // 256 keys per split-K chunk
#define UW 10              // queries per wave in k_attn_part

__device__ __forceinline__ float dot4(float4 a, float4 b) {
    return a.x * b.x + a.y * b.y + a.z * b.z + a.w * b.w;
}

// ---------------- Stage 1: M[b,h,q] = max_s(QK_s) - mean_s(QK_s) ----------------
// quad-per-query: 4 lanes each own 16 d-elements; 2 DPP shuffles per sample.
__global__ __launch_bounds__(256) void k_sampleM(
    const float* __restrict__ Qp, const float* __restrict__ Kp,
    const int* __restrict__ idxs, float* __restrict__ M)
{
    int bh = blockIdx.x & 63;
    int qt = blockIdx.x >> 6;     // 0..31 (64 queries per block)
    int b = bh >> 3, h = bh & 7;
    int t = threadIdx.x;
    int lq = t >> 2;              // 0..63 local query
    int r  = t & 3;               // quad lane: d-range r*16..r*16+15
    int q  = qt * 64 + lq;

    __shared__ int sIdx[64 * Uu];
    for (int i = t; i < 64 * Uu; i += 256)
        sIdx[i] = idxs[(qt * 64) * Uu + i];
    __syncthreads();

    const float4* Qv = reinterpret_cast<const float4*>(
        Qp + (((size_t)b * LQ + q) * Hh + h) * Dd + r * 16);
    float4 q0 = Qv[0], q1 = Qv[1], q2 = Qv[2], q3 = Qv[3];

    float mx = -INFINITY, sm = 0.f;
#pragma unroll 4
    for (int s = 0; s < Uu; ++s) {
        int kidx = sIdx[lq * Uu + s];
        const float4* Kv = reinterpret_cast<const float4*>(
            Kp + (((size_t)b * LK + kidx) * Hh + h) * Dd + r * 16);
        float4 k0 = Kv[0], k1 = Kv[1], k2 = Kv[2], k3 = Kv[3];
        float p = dot4(q0, k0) + dot4(q1, k1) + dot4(q2, k2) + dot4(q3, k3);
        p += __shfl_xor(p, 1, 64);
        p += __shfl_xor(p, 2, 64);
        mx = fmaxf(mx, p);
        sm += p;
    }
    if (r == 0) M[bh * LQ + q] = mx - sm * (1.0f / Uu);
}

// ---------------- Stage 2: top-40 per (b,h), build sel map ----------------
__global__ __launch_bounds__(256) void k_topk(
    const float* __restrict__ M, int* __restrict__ Mtop, int* __restrict__ sel)
{
    int bh = blockIdx.x;
    int t  = threadIdx.x;
    __shared__ float Ml[LQ];
    __shared__ float sv[256];
    __shared__ int   si[256];

    for (int j = t; j < LQ; j += 256) {
        Ml[j] = M[bh * LQ + j];
        sel[bh * LQ + j] = -1;
    }
    __syncthreads();

    for (int u = 0; u < Uu; ++u) {
        float v = -INFINITY; int id = LQ;
        for (int j = t; j < LQ; j += 256) {
            float x = Ml[j];
            if (x > v) { v = x; id = j; }   // ascending j => lowest index on ties
        }
        sv[t] = v; si[t] = id;
        __syncthreads();
        for (int s = 128; s > 0; s >>= 1) {
            if (t < s) {
                float ov = sv[t + s]; int oi = si[t + s];
                if (ov > sv[t] || (ov == sv[t] && oi < si[t])) { sv[t] = ov; si[t] = oi; }
            }
            __syncthreads();
        }
        if (t == 0) {
            int w = si[0];
            Mtop[bh * Uu + u] = w;
            sel[bh * LQ + w] = u;
            Ml[w] = -INFINITY;
        }
        __syncthreads();
    }
}

// ---------------- Stage 3a: split-K partial attention (no max-sub softmax) ----------------
// block = (bh, chunk of 256 keys); each K/V element read by exactly one block.
// wave w handles queries u0..u0+9; lane owns a key for QK, owns a d for PV.
__global__ __launch_bounds__(256) void k_attn_part(
    const float* __restrict__ Qp, const float* __restrict__ Kp,
    const float* __restrict__ Vp, const int* __restrict__ Mtop,
    float* __restrict__ pacc, float* __restrict__ pl)
{
    int bh = blockIdx.x >> 3;
    int c  = blockIdx.x & (NSPL - 1);
    int b = bh >> 3, h = bh & 7;
    int lane = threadIdx.x & 63, wave = threadIdx.x >> 6;

    __shared__ float sQ[Uu][Dd];
    __shared__ int   sP[Uu];
    __shared__ float sE[4][UW][Dd];

    if (threadIdx.x < Uu) sP[threadIdx.x] = Mtop[bh * Uu + threadIdx.x];
    __syncthreads();
    for (int i = threadIdx.x; i < Uu * Dd; i += 256) {
        int u = i >> 6, d = i & 63;
        sQ[u][d] = Qp[(((size_t)b * LQ + sP[u]) * Hh + h) * Dd + d];
    }
    __syncthreads();

    float acc[UW], lsum[UW];
#pragma unroll
    for (int i = 0; i < UW; ++i) { acc[i] = 0.f; lsum[i] = 0.f; }

    const int u0 = wave * UW;
    for (int t = 0; t < CK / 64; ++t) {
        int k0 = c * CK + t * 64;
        int k  = k0 + lane;

        int need = 0;
#pragma unroll
        for (int uu = 0; uu < UW; ++uu) need |= (sP[u0 + uu] >= k0) ? 1 : 0;
        if (!need) continue;   // wave-uniform skip

        // lane's K row into registers
        const float4* Kv = reinterpret_cast<const float4*>(
            Kp + (((size_t)b * LK + k) * Hh + h) * Dd);
        float4 kr[16];
#pragma unroll
        for (int j = 0; j < 16; ++j) kr[j] = Kv[j];

        // QK + exp for active queries (Q broadcast from LDS)
#pragma unroll
        for (int uu = 0; uu < UW; ++uu) {
            int p = sP[u0 + uu];
            if (p < k0) continue;
            const float4* Q4 = reinterpret_cast<const float4*>(sQ[u0 + uu]);
            float s = 0.f;
#pragma unroll
            for (int j = 0; j < 16; ++j) s += dot4(kr[j], Q4[j]);
            float e = (k <= p) ? __expf(s * 0.125f) : 0.f;
            sE[wave][uu][lane] = e;
        }

        // lane's V column (d = lane) for the 64 keys of this tile
        const float* Vb = Vp + (((size_t)b * LK + k0) * Hh + h) * Dd + lane;
        float vc[64];
#pragma unroll
        for (int kk = 0; kk < 64; ++kk) vc[kk] = Vb[(size_t)kk * (Hh * Dd)];

        // PV: weights broadcast from LDS, V column in regs reused across queries
#pragma unroll
        for (int uu = 0; uu < UW; ++uu) {
            int p = sP[u0 + uu];
            if (p < k0) continue;
            const float4* E4 = reinterpret_cast<const float4*>(sE[wave][uu]);
            float a = acc[uu], L = lsum[uu];
#pragma unroll
            for (int j = 0; j < 16; ++j) {
                float4 e4 = E4[j];
                a += e4.x * vc[4 * j + 0] + e4.y * vc[4 * j + 1]
                   + e4.z * vc[4 * j + 2] + e4.w * vc[4 * j + 3];
                L += (e4.x + e4.y) + (e4.z + e4.w);
            }
            acc[uu] = a; lsum[uu] = L;
        }
    }

#pragma unroll
    for (int uu = 0; uu < UW; ++uu) {
        int u = u0 + uu;
        pacc[(((size_t)bh * NSPL + c) * Uu + u) * Dd + lane] = acc[uu];
        if (lane == 0) pl[((size_t)bh * NSPL + c) * Uu + u] = lsum[uu];
    }
}

// ---------------- Stage 3b: combine split-K partials ----------------
__global__ __launch_bounds__(256) void k_attn_comb(
    const float* __restrict__ pacc, const float* __restrict__ pl,
    float* __restrict__ attn)
{
    int gid = blockIdx.x * 4 + (threadIdx.x >> 6);   // one wave per (bh,u)
    int lane = threadIdx.x & 63;
    int bh = gid / Uu, u = gid % Uu;

    float A = 0.f, L = 0.f;
#pragma unroll
    for (int c = 0; c < NSPL; ++c) {
        A += pacc[(((size_t)bh * NSPL + c) * Uu + u) * Dd + lane];
        L += pl[((size_t)bh * NSPL + c) * Uu + u];
    }
    attn[(bh * Uu + u) * Dd + lane] = A / L;
}

// ---------------- Stage 4a: per-chunk partial sums of V along L ----------------
__global__ __launch_bounds__(64) void k_part(
    const float* __restrict__ Vp, float* __restrict__ part)
{
    int c  = blockIdx.x & (NCH - 1);
    int bh = blockIdx.x >> 5;           // NCH = 32
    int b = bh >> 3, h = bh & 7;
    int d = threadIdx.x;

    float s = 0.f;
    int l0 = c * CHUNK;
#pragma unroll 4
    for (int l = l0; l < l0 + CHUNK; ++l)
        s += Vp[(((size_t)b * LK + l) * Hh + h) * Dd + d];
    part[(bh * NCH + c) * Dd + d] = s;
}

// ---------------- Stage 4b: cumsum + scatter attn rows -> output ----------------
__global__ __launch_bounds__(64) void k_scan(
    const float* __restrict__ Vp, const float* __restrict__ part,
    const int* __restrict__ sel, const float* __restrict__ attn,
    float* __restrict__ out)
{
    int c  = blockIdx.x & (NCH - 1);
    int bh = blockIdx.x >> 5;
    int b = bh >> 3, h = bh & 7;
    int d = threadIdx.x;

    float run = 0.f;
    for (int cc = 0; cc < c; ++cc)
        run += part[(bh * NCH + cc) * Dd + d];

    int l0 = c * CHUNK;
    for (int l = l0; l < l0 + CHUNK; ++l) {
        run += Vp[(((size_t)b * LK + l) * Hh + h) * Dd + d];
        int s = sel[bh * LQ + l];
        float o = (s >= 0) ? attn[(bh * Uu + s) * Dd + d] : run;
        out[(((size_t)b * LQ + l) * Hh + h) * Dd + d] = o;
    }
}

extern "C" void kernel_launch(void* const* d_in, const int* in_sizes, int n_in,
                              void* d_out, int out_size, void* d_ws, size_t ws_size,
                              hipStream_t stream) {
    const float* Qp   = (const float*)d_in[0];
    const float* Kp   = (const float*)d_in[1];
    const float* Vp   = (const float*)d_in[2];
    const int*   idxs = (const int*)d_in[3];
    float* out = (float*)d_out;

    char* w = (char*)d_ws;
    float* M    = (float*)(w);                               // 512K
    int*   sel  = (int*)  (w + 512 * 1024);                  // 512K
    float* attn = (float*)(w + 1024 * 1024);                 // 640K
    int*   Mtop = (int*)  (w + 1664 * 1024);                 // 16K
    float* part = (float*)(w + 1680 * 1024);                 // 512K
    float* pacc = (float*)(w + 2304 * 1024);                 // 5.24M (64*8*40*64 f)
    float* pl   = (float*)(w + 7680 * 1024);                 // 80K   (64*8*40 f)

    k_sampleM<<<Bb * Hh * (LQ / 64), 256, 0, stream>>>(Qp, Kp, idxs, M);
    k_topk<<<Bb * Hh, 256, 0, stream>>>(M, Mtop, sel);
    k_attn_part<<<Bb * Hh * NSPL, 256, 0, stream>>>(Qp, Kp, Vp, Mtop, pacc, pl);
    k_attn_comb<<<(Bb * Hh * Uu) / 4, 256, 0, stream>>>(pacc, pl, attn);
    k_part<<<Bb * Hh * NCH, 64, 0, stream>>>(Vp, part);
    k_scan<<<Bb * Hh * NCH, 64, 0, stream>>>(Vp, part, sel, attn, out);
}

// Round 4
// 195.419 us; speedup vs baseline: 4.1961x; 1.2345x over previous
//
#include <hip/hip_runtime.h>
#include <math.h>

#define Bb 8
#define Hh 8
#define LQ 2048
#define LK 2048
#define Dd 64
#define Uu 40
#define NCH 32
#define CHUNK (LK / NCH)   // 64
#define NSPL 8
#define CK (LK / NSPL)     // 256 keys per split-K chunk
#define UW 10              // queries per wave in k_attn_part

__device__ __forceinline__ float dot4(float4 a, float4 b) {
    return a.x * b.x + a.y * b.y + a.z * b.z + a.w * b.w;
}

// ---------------- Stage 1: M[b,h,q] = max_s(QK_s) - mean_s(QK_s) ----------------
// block = (b, 16 queries); one coalesced 2KB K-chunk read serves all 8 heads.
// lane owns 8 contiguous floats (head = lane/8); reduce via 3 shfl_xor in 8-lane groups.
__global__ __launch_bounds__(256) void k_sampleM(
    const float* __restrict__ Qp, const float* __restrict__ Kp,
    const int* __restrict__ idxs, float* __restrict__ M)
{
    int b  = blockIdx.x & 7;      // b-major: round-robin XCD dispatch pins K[b] (4MB) per XCD L2
    int qt = blockIdx.x >> 3;     // 0..127
    int t = threadIdx.x;
    int lane = t & 63, wave = t >> 6;

    __shared__ int sIdx[16 * Uu];
    for (int i = t; i < 16 * Uu; i += 256)
        sIdx[i] = idxs[(qt * 16) * Uu + i];
    __syncthreads();

    const size_t HD = (size_t)Hh * Dd;   // 512
#pragma unroll
    for (int i = 0; i < 4; ++i) {
        int lq = wave * 4 + i;
        int q  = qt * 16 + lq;
        const float4* Qv = reinterpret_cast<const float4*>(
            Qp + ((size_t)b * LQ + q) * HD + lane * 8);
        float4 qa = Qv[0], qb = Qv[1];

        float mx = -INFINITY, sm = 0.f;
#pragma unroll 8
        for (int s = 0; s < Uu; ++s) {
            int kidx = sIdx[lq * Uu + s];
            const float4* Kv = reinterpret_cast<const float4*>(
                Kp + ((size_t)b * LK + kidx) * HD + lane * 8);
            float4 ka = Kv[0], kb = Kv[1];
            float p = dot4(qa, ka) + dot4(qb, kb);
            p += __shfl_xor(p, 1, 64);
            p += __shfl_xor(p, 2, 64);
            p += __shfl_xor(p, 4, 64);
            mx = fmaxf(mx, p);
            sm += p;
        }
        if ((lane & 7) == 0) {
            int h = lane >> 3;
            M[((b * 8 + h) << 11) + q] = mx - sm * (1.0f / Uu);
        }
    }
}

// ---------------- Stage 2: top-40 per (b,h) — single wave, shuffle argmax, 0 barriers ----
__global__ __launch_bounds__(64) void k_topk(
    const float* __restrict__ M, int* __restrict__ Mtop, int* __restrict__ sel)
{
    int bh = blockIdx.x;
    int lane = threadIdx.x;
    __shared__ float Ml[LQ];

    for (int j = lane; j < LQ; j += 64) {
        Ml[j] = M[bh * LQ + j];
        sel[bh * LQ + j] = -1;
    }
    __syncthreads();

    // lane's local best over its column (indices lane + 64*j, ascending => lowest-idx ties)
    float lv = -INFINITY; int li = LQ;
    for (int j = 0; j < 32; ++j) {
        int idx = lane + 64 * j;
        float x = Ml[idx];
        if (x > lv) { lv = x; li = idx; }
    }

    for (int u = 0; u < Uu; ++u) {
        float v = lv; int id = li;
#pragma unroll
        for (int off = 32; off > 0; off >>= 1) {
            float ov = __shfl_xor(v, off, 64);
            int   oi = __shfl_xor(id, off, 64);
            if (ov > v || (ov == v && oi < id)) { v = ov; id = oi; }
        }
        // all lanes now agree on (v, id); reference tie-break (lowest index) preserved
        if (lane == 0) {
            Mtop[bh * Uu + u] = id;
            sel[bh * LQ + id] = u;
        }
        if ((id & 63) == lane) {        // owner invalidates + rescans its column
            Ml[id] = -INFINITY;
            lv = -INFINITY; li = LQ;
            for (int j = 0; j < 32; ++j) {
                int idx = lane + 64 * j;
                float x = Ml[idx];
                if (x > lv) { lv = x; li = idx; }
            }
        }
    }
}

// ---------------- Stage 3a: split-K partial attention (no max-sub softmax) ----------------
__global__ __launch_bounds__(256) void k_attn_part(
    const float* __restrict__ Qp, const float* __restrict__ Kp,
    const float* __restrict__ Vp, const int* __restrict__ Mtop,
    float* __restrict__ pacc, float* __restrict__ pl)
{
    int bh = blockIdx.x >> 3;
    int c  = blockIdx.x & (NSPL - 1);
    int b = bh >> 3, h = bh & 7;
    int lane = threadIdx.x & 63, wave = threadIdx.x >> 6;

    __shared__ float sQ[Uu][Dd];
    __shared__ int   sP[Uu];
    __shared__ float sE[4][UW][Dd];

    if (threadIdx.x < Uu) sP[threadIdx.x] = Mtop[bh * Uu + threadIdx.x];
    __syncthreads();
    for (int i = threadIdx.x; i < Uu * Dd; i += 256) {
        int u = i >> 6, d = i & 63;
        sQ[u][d] = Qp[(((size_t)b * LQ + sP[u]) * Hh + h) * Dd + d];
    }
    __syncthreads();

    float acc[UW], lsum[UW];
#pragma unroll
    for (int i = 0; i < UW; ++i) { acc[i] = 0.f; lsum[i] = 0.f; }

    const int u0 = wave * UW;
    for (int t = 0; t < CK / 64; ++t) {
        int k0 = c * CK + t * 64;
        int k  = k0 + lane;

        int need = 0;
#pragma unroll
        for (int uu = 0; uu < UW; ++uu) need |= (sP[u0 + uu] >= k0) ? 1 : 0;
        if (!need) continue;   // wave-uniform skip

        const float4* Kv = reinterpret_cast<const float4*>(
            Kp + (((size_t)b * LK + k) * Hh + h) * Dd);
        float4 kr[16];
#pragma unroll
        for (int j = 0; j < 16; ++j) kr[j] = Kv[j];

#pragma unroll
        for (int uu = 0; uu < UW; ++uu) {
            int p = sP[u0 + uu];
            if (p < k0) continue;
            const float4* Q4 = reinterpret_cast<const float4*>(sQ[u0 + uu]);
            float s = 0.f;
#pragma unroll
            for (int j = 0; j < 16; ++j) s += dot4(kr[j], Q4[j]);
            float e = (k <= p) ? __expf(s * 0.125f) : 0.f;
            sE[wave][uu][lane] = e;
        }

        const float* Vb = Vp + (((size_t)b * LK + k0) * Hh + h) * Dd + lane;
        float vc[64];
#pragma unroll
        for (int kk = 0; kk < 64; ++kk) vc[kk] = Vb[(size_t)kk * (Hh * Dd)];

#pragma unroll
        for (int uu = 0; uu < UW; ++uu) {
            int p = sP[u0 + uu];
            if (p < k0) continue;
            const float4* E4 = reinterpret_cast<const float4*>(sE[wave][uu]);
            float a = acc[uu], L = lsum[uu];
#pragma unroll
            for (int j = 0; j < 16; ++j) {
                float4 e4 = E4[j];
                a += e4.x * vc[4 * j + 0] + e4.y * vc[4 * j + 1]
                   + e4.z * vc[4 * j + 2] + e4.w * vc[4 * j + 3];
                L += (e4.x + e4.y) + (e4.z + e4.w);
            }
            acc[uu] = a; lsum[uu] = L;
        }
    }

#pragma unroll
    for (int uu = 0; uu < UW; ++uu) {
        int u = u0 + uu;
        pacc[(((size_t)bh * NSPL + c) * Uu + u) * Dd + lane] = acc[uu];
        if (lane == 0) pl[((size_t)bh * NSPL + c) * Uu + u] = lsum[uu];
    }
}

// ---------------- Stage 3b: combine split-K partials ----------------
__global__ __launch_bounds__(256) void k_attn_comb(
    const float* __restrict__ pacc, const float* __restrict__ pl,
    float* __restrict__ attn)
{
    int gid = blockIdx.x * 4 + (threadIdx.x >> 6);
    int lane = threadIdx.x & 63;
    int bh = gid / Uu, u = gid % Uu;

    float A = 0.f, L = 0.f;
#pragma unroll
    for (int c = 0; c < NSPL; ++c) {
        A += pacc[(((size_t)bh * NSPL + c) * Uu + u) * Dd + lane];
        L += pl[((size_t)bh * NSPL + c) * Uu + u];
    }
    attn[(bh * Uu + u) * Dd + lane] = A / L;
}

// ---------------- Stage 4a: per-chunk partial sums of V (float4, 16dq x 4r) -------------
__global__ __launch_bounds__(64) void k_part(
    const float* __restrict__ Vp, float* __restrict__ part)
{
    int c  = blockIdx.x & (NCH - 1);
    int bh = blockIdx.x >> 5;
    int b = bh >> 3, h = bh & 7;
    int dq = threadIdx.x & 15, r = threadIdx.x >> 4;

    const float* vb = Vp + (((size_t)b * LK + c * CHUNK) * Hh + h) * Dd + dq * 4;
    float sx = 0.f, sy = 0.f, sz = 0.f, sw = 0.f;
    for (int l = r; l < CHUNK; l += 4) {
        float4 v = *reinterpret_cast<const float4*>(vb + (size_t)l * (Hh * Dd));
        sx += v.x; sy += v.y; sz += v.z; sw += v.w;
    }
    sx += __shfl_xor(sx, 16, 64); sy += __shfl_xor(sy, 16, 64);
    sz += __shfl_xor(sz, 16, 64); sw += __shfl_xor(sw, 16, 64);
    sx += __shfl_xor(sx, 32, 64); sy += __shfl_xor(sy, 32, 64);
    sz += __shfl_xor(sz, 32, 64); sw += __shfl_xor(sw, 32, 64);
    if (r == 0) {
        float4 s4 = make_float4(sx, sy, sz, sw);
        *reinterpret_cast<float4*>(&part[(size_t)(bh * NCH + c) * Dd + dq * 4]) = s4;
    }
}

// ---------------- Stage 4b: exclusive prefix over chunks ----------------
__global__ __launch_bounds__(64) void k_prefix(
    const float* __restrict__ part, float* __restrict__ pfx)
{
    int bh = blockIdx.x;
    int d = threadIdx.x;
    float run = 0.f;
    for (int c = 0; c < NCH; ++c) {
        pfx[(size_t)(bh * NCH + c) * Dd + d] = run;
        run += part[(size_t)(bh * NCH + c) * Dd + d];
    }
}

// ---------------- Stage 4c: cumsum + scatter attn rows -> output ----------------
__global__ __launch_bounds__(64) void k_scan(
    const float* __restrict__ Vp, const float* __restrict__ pfx,
    const int* __restrict__ sel, const float* __restrict__ attn,
    float* __restrict__ out)
{
    int c  = blockIdx.x & (NCH - 1);
    int bh = blockIdx.x >> 5;
    int b = bh >> 3, h = bh & 7;
    int d = threadIdx.x;

    float run = pfx[(size_t)(bh * NCH + c) * Dd + d];
    int l0 = c * CHUNK;
    const float* vb = Vp + (((size_t)b * LK + l0) * Hh + h) * Dd + d;
    float* ob = out + (((size_t)b * LQ + l0) * Hh + h) * Dd + d;
    const int* sb = sel + bh * LQ + l0;

#pragma unroll 4
    for (int l = 0; l < CHUNK; ++l) {
        float v = vb[(size_t)l * (Hh * Dd)];
        int s = sb[l];
        int si = (s >= 0) ? s : 0;
        float av = attn[(bh * Uu + si) * Dd + d];
        run += v;
        ob[(size_t)l * (Hh * Dd)] = (s >= 0) ? av : run;
    }
}

extern "C" void kernel_launch(void* const* d_in, const int* in_sizes, int n_in,
                              void* d_out, int out_size, void* d_ws, size_t ws_size,
                              hipStream_t stream) {
    const float* Qp   = (const float*)d_in[0];
    const float* Kp   = (const float*)d_in[1];
    const float* Vp   = (const float*)d_in[2];
    const int*   idxs = (const int*)d_in[3];
    float* out = (float*)d_out;

    char* w = (char*)d_ws;
    float* M    = (float*)(w);                 // 512K (dead after k_topk -> reused as pfx)
    int*   sel  = (int*)  (w + 512 * 1024);    // 512K
    float* attn = (float*)(w + 1024 * 1024);   // 640K
    int*   Mtop = (int*)  (w + 1664 * 1024);   // 16K
    float* part = (float*)(w + 1680 * 1024);   // 512K
    float* pacc = (float*)(w + 2304 * 1024);   // 5120K (64*8*40*64 f)
    float* pl   = (float*)(w + 7424 * 1024);   // 80K
    float* pfx  = M;                           // reuse (M dead after k_topk)

    k_sampleM<<<Bb * (LQ / 16), 256, 0, stream>>>(Qp, Kp, idxs, M);
    k_topk<<<Bb * Hh, 64, 0, stream>>>(M, Mtop, sel);
    k_attn_part<<<Bb * Hh * NSPL, 256, 0, stream>>>(Qp, Kp, Vp, Mtop, pacc, pl);
    k_attn_comb<<<(Bb * Hh * Uu) / 4, 256, 0, stream>>>(pacc, pl, attn);
    k_part<<<Bb * Hh * NCH, 64, 0, stream>>>(Vp, part);
    k_prefix<<<Bb * Hh, 64, 0, stream>>>(part, pfx);
    k_scan<<<Bb * Hh * NCH, 64, 0, stream>>>(Vp, pfx, sel, attn, out);
}